// Round 5
// baseline (231.831 us; speedup 1.0000x reference)
//
#include <hip/hip_runtime.h>

// HybridLoss: param smooth-L1 mean + 0.5*(1 - mean(box overlap))
// B = 2,000,000 rows x 10 f32 params (c[3], d[3], q[4]) per side.
//
// Round-3 lesson: direct per-row loads (40-B lane stride) are transaction-
// bound (~64 line-touches per VMEM instr, 13% HBM). This version stages
// 512-row chunks into LDS with fully-coalesced global_load_lds (width 16),
// then reads rows from LDS (<=4-way bank conflicts on float2, negligible).

#define B_ROWS 2000000
#define THREADS 512
#define CHUNK_ROWS 512
#define CHUNK_F4 1280                 // 512 rows * 40 B / 16 B
#define N_CHUNKS 3907                 // ceil(2e6 / 512)
constexpr float OVERLAP_WEIGHT = 0.5f;
constexpr float EPS_F = 1e-6f;
constexpr size_t TOTAL_F4 = (size_t)B_ROWS * 40 / 16;   // 5,000,000 float4s per side

__device__ __forceinline__ void gload_lds16(const float* g, float* l) {
    // direct global->LDS, 16 B per lane; LDS dest = wave-uniform base + lane*16
    __builtin_amdgcn_global_load_lds(
        (const __attribute__((address_space(1))) void*)g,
        (__attribute__((address_space(3))) void*)l, 16, 0, 0);
}

__device__ __forceinline__ void quat_to_rot(float x, float y, float z, float w,
                                            float R[9]) {
    R[0] = 1.f - 2.f*y*y - 2.f*z*z;
    R[1] = 2.f*x*y + 2.f*z*w;
    R[2] = 2.f*x*z - 2.f*y*w;
    R[3] = 2.f*x*y - 2.f*z*w;
    R[4] = 1.f - 2.f*x*x - 2.f*z*z;
    R[5] = 2.f*y*z + 2.f*x*w;
    R[6] = 2.f*x*z + 2.f*y*w;
    R[7] = 2.f*y*z - 2.f*x*w;
    R[8] = 1.f - 2.f*x*x - 2.f*y*y;
}

__global__ __launch_bounds__(THREADS) void hybrid_loss_main(
    const float* __restrict__ preds, const float* __restrict__ targets,
    float* __restrict__ acc)  // acc[0] = smooth-L1 sum, acc[1] = overlap sum
{
    // 2 x 20480 B = 40960 B -> exactly 4 blocks/CU (160 KiB LDS)
    __shared__ __align__(16) float ldsP[CHUNK_F4 * 4];
    __shared__ __align__(16) float ldsT[CHUNK_F4 * 4];

    const int tid  = threadIdx.x;
    const int wave = tid >> 6;
    const int lane = tid & 63;
    const int c    = blockIdx.x;
    const size_t base_f4 = (size_t)c * CHUNK_F4;

    // ---- stage chunk: 1280 float4/side = 2 full rounds (512 f4) + 1 half ----
    #pragma unroll
    for (int r = 0; r < 2; ++r) {
        const int e_wave = r * 512 + wave * 64;      // wave-uniform f4 base
        size_t gidx = base_f4 + e_wave + lane;       // per-lane f4 index
        if (gidx >= TOTAL_F4) gidx = TOTAL_F4 - 1;   // clamp (tail chunk)
        gload_lds16(preds   + gidx * 4, &ldsP[e_wave * 4]);
        gload_lds16(targets + gidx * 4, &ldsT[e_wave * 4]);
    }
    if (wave < 4) {                                  // wave-uniform branch
        const int e_wave = 1024 + wave * 64;
        size_t gidx = base_f4 + e_wave + lane;
        if (gidx >= TOTAL_F4) gidx = TOTAL_F4 - 1;
        gload_lds16(preds   + gidx * 4, &ldsP[e_wave * 4]);
        gload_lds16(targets + gidx * 4, &ldsT[e_wave * 4]);
    }
    __syncthreads();   // drains vmcnt before barrier (compiler-emitted)

    // ---- compute: one row per thread, read from LDS ----
    float psum = 0.f, osum = 0.f;
    const size_t grow = (size_t)c * CHUNK_ROWS + tid;
    if (grow < B_ROWS) {
        float p[10], t[10];
        const float2* lp = reinterpret_cast<const float2*>(&ldsP[tid * 10]);
        const float2* lt = reinterpret_cast<const float2*>(&ldsT[tid * 10]);
        #pragma unroll
        for (int i = 0; i < 5; ++i) {
            float2 a = lp[i]; p[2*i] = a.x; p[2*i+1] = a.y;
            float2 b = lt[i]; t[2*i] = b.x; t[2*i+1] = b.y;
        }

        // smooth L1 over all 10 params
        #pragma unroll
        for (int i = 0; i < 10; ++i) {
            float d  = p[i] - t[i];
            float ad = fabsf(d);
            psum += (ad < 1.f) ? 0.5f * d * d : ad - 0.5f;
        }

        // overlap
        float pqn = sqrtf(p[6]*p[6] + p[7]*p[7] + p[8]*p[8] + p[9]*p[9]);
        float tqn = sqrtf(t[6]*t[6] + t[7]*t[7] + t[8]*t[8] + t[9]*t[9]);
        float pri = 1.f / pqn, tri = 1.f / tqn;
        float PR[9], TR[9];
        quat_to_rot(p[6]*pri, p[7]*pri, p[8]*pri, p[9]*pri, PR);
        quat_to_rot(t[6]*tri, t[7]*tri, t[8]*tri, t[9]*tri, TR);

        float ra = 0.f;
        #pragma unroll
        for (int i = 0; i < 9; ++i) ra += PR[i] * TR[i];
        ra = fminf(fmaxf(ra * (1.f/3.f), 0.f), 1.f);

        float ov = ra;
        #pragma unroll
        for (int i = 0; i < 3; ++i) {
            float pe = fabsf(PR[3*i+0]*(p[3]*0.5f) + PR[3*i+1]*(p[4]*0.5f) + PR[3*i+2]*(p[5]*0.5f));
            float te = fabsf(TR[3*i+0]*(t[3]*0.5f) + TR[3*i+1]*(t[4]*0.5f) + TR[3*i+2]*(t[5]*0.5f));
            float cd = fabsf(p[i] - t[i]);
            float ax = fmaxf(fminf(pe, te) * 2.f - cd, 0.f) / (pe + te + EPS_F);
            ov *= ax;
        }
        ov = fminf(fmaxf(ov, 0.f), 1.f);
        osum += ov;
    }

    // ---- reduction: wave shuffle, then cross-wave via (reused) LDS ----
    #pragma unroll
    for (int off = 32; off > 0; off >>= 1) {
        psum += __shfl_down(psum, off);
        osum += __shfl_down(osum, off);
    }
    __syncthreads();                   // compute done; safe to reuse ldsP
    if (lane == 0) { ldsP[wave] = psum; ldsP[8 + wave] = osum; }
    __syncthreads();
    if (tid == 0) {
        float P = 0.f, O = 0.f;
        #pragma unroll
        for (int w = 0; w < 8; ++w) { P += ldsP[w]; O += ldsP[8 + w]; }
        atomicAdd(&acc[0], P);
        atomicAdd(&acc[1], O);
    }
}

__global__ void hybrid_loss_finalize(const float* __restrict__ acc,
                                     float* __restrict__ out) {
    out[0] = acc[0] * (1.f / (10.f * (float)B_ROWS))
           + OVERLAP_WEIGHT * (1.f - acc[1] * (1.f / (float)B_ROWS));
}

extern "C" void kernel_launch(void* const* d_in, const int* in_sizes, int n_in,
                              void* d_out, int out_size, void* d_ws, size_t ws_size,
                              hipStream_t stream) {
    const float* preds   = (const float*)d_in[0];
    const float* targets = (const float*)d_in[1];
    float* out = (float*)d_out;
    float* acc = (float*)d_ws;

    hipMemsetAsync(acc, 0, 2 * sizeof(float), stream);

    hybrid_loss_main<<<N_CHUNKS, THREADS, 0, stream>>>(preds, targets, acc);
    hybrid_loss_finalize<<<1, 1, 0, stream>>>(acc, out);
}

// Round 6
// 210.895 us; speedup vs baseline: 1.0993x; 1.0993x over previous
//
#include <hip/hip_runtime.h>

// HybridLoss: param smooth-L1 mean + 0.5*(1 - mean(box overlap))
// B = 2,000,000 rows x 10 f32 (c[3], d[3], q[4]) per side.
//
// R3: per-row direct loads -> transaction-bound (40-B rows vs 64-B lines,
//     ~5x line re-touch), 76 us, 13% HBM.
// R5: global_load_lds staging in tiny blocks -> vmcnt(0) drain at barrier,
//     zero overlap, latency-bound, 112 us.
// R6 (this): persistent blocks + striped dense float4 global->REG loads
//     (ideal coalescing) + ds_write->LDS + row reads from LDS, software-
//     pipelined (T14): next chunk's loads issued before computing current
//     chunk; vmcnt wait lands at next ds_write, hidden under compute.

#define B_ROWS 2000000
#define THREADS 256
#define CHUNK_ROWS 512
#define CHUNK_F4 1280                  // 512 rows * 40 B / 16 B per side
#define N_CHUNKS 3907                  // ceil(2e6 / 512)
#define GRID 1024                      // 4 blocks/CU (LDS-limited), persistent
constexpr float OVERLAP_WEIGHT = 0.5f;
constexpr float EPS_F = 1e-6f;
constexpr int TOTAL_F4 = 5000000;      // per side: 2e6*40/16

__device__ __forceinline__ void quat_to_rot(float x, float y, float z, float w,
                                            float R[9]) {
    R[0] = 1.f - 2.f*y*y - 2.f*z*z;
    R[1] = 2.f*x*y + 2.f*z*w;
    R[2] = 2.f*x*z - 2.f*y*w;
    R[3] = 2.f*x*y - 2.f*z*w;
    R[4] = 1.f - 2.f*x*x - 2.f*z*z;
    R[5] = 2.f*y*z + 2.f*x*w;
    R[6] = 2.f*x*z + 2.f*y*w;
    R[7] = 2.f*y*z - 2.f*x*w;
    R[8] = 1.f - 2.f*x*x - 2.f*y*y;
}

__global__ __launch_bounds__(THREADS) void hybrid_loss_main(
    const float4* __restrict__ preds4, const float4* __restrict__ targets4,
    float* __restrict__ acc)  // acc[0] = smooth-L1 sum, acc[1] = overlap sum
{
    // 2 x 20480 B = 40960 B -> exactly 4 blocks/CU (160 KiB LDS). No extra
    // shared arrays (would round LDS up and drop to 3 blocks/CU).
    __shared__ __align__(16) float4 ldsP[CHUNK_F4];
    __shared__ __align__(16) float4 ldsT[CHUNK_F4];

    const int tid  = threadIdx.x;
    const int wave = tid >> 6;
    const int lane = tid & 63;
    const int spos = wave * 320 + lane;      // + i*64, i=0..4 -> 0..1279

    float4 rp[5], rt[5];
    float psum = 0.f, osum = 0.f;

    int c = blockIdx.x;
    {   // initial (unoverlapped) load: dense striped float4, 16 lines/instr
        const int gb = c * CHUNK_F4;
        #pragma unroll
        for (int i = 0; i < 5; ++i) {
            int idx = gb + spos + i * 64;
            if (idx >= TOTAL_F4) idx = TOTAL_F4 - 1;   // tail clamp
            rp[i] = preds4[idx];
            rt[i] = targets4[idx];
        }
    }

    while (true) {
        // ---- write staged regs to LDS (s_waitcnt vmcnt lands here, after
        //      a full compute phase for all but the first iteration) ----
        #pragma unroll
        for (int i = 0; i < 5; ++i) {
            ldsP[spos + i * 64] = rp[i];
            ldsT[spos + i * 64] = rt[i];
        }
        __syncthreads();

        // ---- issue next chunk's global loads (not waited until next write)
        const int cn = c + GRID;
        const bool more = (cn < N_CHUNKS);           // block-uniform
        if (more) {
            const int gb = cn * CHUNK_F4;
            #pragma unroll
            for (int i = 0; i < 5; ++i) {
                int idx = gb + spos + i * 64;
                if (idx >= TOTAL_F4) idx = TOTAL_F4 - 1;
                rp[i] = preds4[idx];
                rt[i] = targets4[idx];
            }
        }

        // ---- compute current chunk from LDS: 2 rows per thread ----
        const int rowbase = c * CHUNK_ROWS;
        #pragma unroll
        for (int k = 0; k < 2; ++k) {
            const int rr = tid + k * 256;            // 0..511
            if (rowbase + rr < B_ROWS) {
                float p[10], t[10];
                const float2* lp = reinterpret_cast<const float2*>(
                    reinterpret_cast<const float*>(ldsP) + rr * 10);
                const float2* lt = reinterpret_cast<const float2*>(
                    reinterpret_cast<const float*>(ldsT) + rr * 10);
                #pragma unroll
                for (int i = 0; i < 5; ++i) {
                    float2 a = lp[i]; p[2*i] = a.x; p[2*i+1] = a.y;
                    float2 b = lt[i]; t[2*i] = b.x; t[2*i+1] = b.y;
                }

                // smooth L1
                #pragma unroll
                for (int i = 0; i < 10; ++i) {
                    float d  = p[i] - t[i];
                    float ad = fabsf(d);
                    psum += (ad < 1.f) ? 0.5f * d * d : ad - 0.5f;
                }

                // overlap
                float pqn = sqrtf(p[6]*p[6] + p[7]*p[7] + p[8]*p[8] + p[9]*p[9]);
                float tqn = sqrtf(t[6]*t[6] + t[7]*t[7] + t[8]*t[8] + t[9]*t[9]);
                float pri = 1.f / pqn, tri = 1.f / tqn;
                float PR[9], TR[9];
                quat_to_rot(p[6]*pri, p[7]*pri, p[8]*pri, p[9]*pri, PR);
                quat_to_rot(t[6]*tri, t[7]*tri, t[8]*tri, t[9]*tri, TR);

                float ra = 0.f;
                #pragma unroll
                for (int i = 0; i < 9; ++i) ra += PR[i] * TR[i];
                ra = fminf(fmaxf(ra * (1.f/3.f), 0.f), 1.f);

                float ov = ra;
                #pragma unroll
                for (int i = 0; i < 3; ++i) {
                    float pe = fabsf(PR[3*i+0]*(p[3]*0.5f) + PR[3*i+1]*(p[4]*0.5f) + PR[3*i+2]*(p[5]*0.5f));
                    float te = fabsf(TR[3*i+0]*(t[3]*0.5f) + TR[3*i+1]*(t[4]*0.5f) + TR[3*i+2]*(t[5]*0.5f));
                    float cd = fabsf(p[i] - t[i]);
                    float ax = fmaxf(fminf(pe, te) * 2.f - cd, 0.f) / (pe + te + EPS_F);
                    ov *= ax;
                }
                ov = fminf(fmaxf(ov, 0.f), 1.f);
                osum += ov;
            }
        }
        __syncthreads();                 // all LDS reads done before overwrite
        if (!more) break;
        c = cn;
    }

    // ---- reduction: wave shuffle, cross-wave via reused LDS ----
    #pragma unroll
    for (int off = 32; off > 0; off >>= 1) {
        psum += __shfl_down(psum, off);
        osum += __shfl_down(osum, off);
    }
    float* red = reinterpret_cast<float*>(ldsP);   // loop ended post-barrier
    if (lane == 0) { red[wave] = psum; red[4 + wave] = osum; }
    __syncthreads();
    if (tid == 0) {
        float P = red[0] + red[1] + red[2] + red[3];
        float O = red[4] + red[5] + red[6] + red[7];
        atomicAdd(&acc[0], P);
        atomicAdd(&acc[1], O);
    }
}

__global__ void hybrid_loss_finalize(const float* __restrict__ acc,
                                     float* __restrict__ out) {
    out[0] = acc[0] * (1.f / (10.f * (float)B_ROWS))
           + OVERLAP_WEIGHT * (1.f - acc[1] * (1.f / (float)B_ROWS));
}

extern "C" void kernel_launch(void* const* d_in, const int* in_sizes, int n_in,
                              void* d_out, int out_size, void* d_ws, size_t ws_size,
                              hipStream_t stream) {
    const float4* preds4   = (const float4*)d_in[0];
    const float4* targets4 = (const float4*)d_in[1];
    float* out = (float*)d_out;
    float* acc = (float*)d_ws;

    hipMemsetAsync(acc, 0, 2 * sizeof(float), stream);

    hybrid_loss_main<<<GRID, THREADS, 0, stream>>>(preds4, targets4, acc);
    hybrid_loss_finalize<<<1, 1, 0, stream>>>(acc, out);
}

// Round 10
// 191.213 us; speedup vs baseline: 1.2124x; 1.1029x over previous
//
#include <hip/hip_runtime.h>

// HybridLoss: param smooth-L1 mean + 0.5*(1 - mean(box overlap))
// B = 2,000,000 rows x 10 f32 (c[3], d[3], q[4]) per side.
//
// R3: per-row direct loads -> transaction-bound (40-B rows vs 64-B lines), 76us.
// R5: global_load_lds, tiny blocks, no overlap -> latency-bound, 112us.
// R6: reg-staged pipeline -> compiler spilled the 40 prefetch VGPRs to
//     scratch (WRITE_SIZE 152 MB parasitic), 97us.
// R7 (this): double-buffered global_load_lds (NO VGPR round-trip -> nothing
//     to spill) + persistent blocks. Stage buf[cur^1] BEFORE computing
//     buf[cur]; the __syncthreads vmcnt-drain lands after a full compute
//     phase, hiding HBM latency (T3 minimum 2-phase).

#define B_ROWS 2000000
#define THREADS 256
#define CHUNK_ROWS 256
#define F4_SIDE 640                    // 256 rows * 40 B / 16 B per side
#define N_CHUNKS 7813                  // ceil(2e6 / 256)
#define GRID 1024                      // persistent, 4 blocks/CU (LDS-limited)
constexpr float OVERLAP_WEIGHT = 0.5f;
constexpr float EPS_F = 1e-6f;
constexpr int TOTAL_F4 = 5000000;      // per side

__device__ __forceinline__ void gload_lds16(const float4* g, float4* l) {
    // LDS dest is wave-uniform base; HW writes lane i at dest + i*16.
    __builtin_amdgcn_global_load_lds(
        (const __attribute__((address_space(1))) void*)g,
        (__attribute__((address_space(3))) void*)l, 16, 0, 0);
}

__device__ __forceinline__ void quat_to_rot(float x, float y, float z, float w,
                                            float R[9]) {
    R[0] = 1.f - 2.f*y*y - 2.f*z*z;
    R[1] = 2.f*x*y + 2.f*z*w;
    R[2] = 2.f*x*z - 2.f*y*w;
    R[3] = 2.f*x*y - 2.f*z*w;
    R[4] = 1.f - 2.f*x*x - 2.f*z*z;
    R[5] = 2.f*y*z + 2.f*x*w;
    R[6] = 2.f*x*z + 2.f*y*w;
    R[7] = 2.f*y*z - 2.f*x*w;
    R[8] = 1.f - 2.f*x*x - 2.f*y*y;
}

__global__ __launch_bounds__(THREADS) void hybrid_loss_main(
    const float4* __restrict__ preds4, const float4* __restrict__ targets4,
    float* __restrict__ acc)  // acc[0] = smooth-L1 sum, acc[1] = overlap sum
{
    // [buf][side][f4]: 2*2*640*16 B = 40960 B -> exactly 4 blocks/CU.
    __shared__ __align__(16) float4 lds[2][2][F4_SIDE];

    const int tid  = threadIdx.x;
    const int wave = tid >> 6;
    const int lane = tid & 63;

    float psum = 0.f, osum = 0.f;

    // stage chunk c into lds[buf]: 10 rounds of 64 f4 per side, wave-cyclic
    auto stage = [&](int buf, int c) {
        const int gb = c * F4_SIDE;
        for (int r = wave; r < 10; r += 4) {         // wave-uniform loop
            int idx = gb + r * 64 + lane;
            if (idx >= TOTAL_F4) idx = TOTAL_F4 - 1; // per-lane src clamp ok
            gload_lds16(preds4   + idx, &lds[buf][0][r * 64]);
            gload_lds16(targets4 + idx, &lds[buf][1][r * 64]);
        }
    };

    int c = blockIdx.x;
    int cur = 0;
    stage(0, c);
    __syncthreads();                                 // prologue drain (once)

    while (true) {
        const int cn = c + GRID;
        const bool more = (cn < N_CHUNKS);           // block-uniform
        if (more) stage(cur ^ 1, cn);                // issue next; not waited

        // ---- compute current chunk: 1 row per thread, from LDS ----
        if (c * CHUNK_ROWS + tid < B_ROWS) {
            float p[10], t[10];
            const float2* lp = reinterpret_cast<const float2*>(
                reinterpret_cast<const float*>(&lds[cur][0][0]) + tid * 10);
            const float2* lt = reinterpret_cast<const float2*>(
                reinterpret_cast<const float*>(&lds[cur][1][0]) + tid * 10);
            #pragma unroll
            for (int i = 0; i < 5; ++i) {
                float2 a = lp[i]; p[2*i] = a.x; p[2*i+1] = a.y;
                float2 b = lt[i]; t[2*i] = b.x; t[2*i+1] = b.y;
            }

            // smooth L1
            #pragma unroll
            for (int i = 0; i < 10; ++i) {
                float d  = p[i] - t[i];
                float ad = fabsf(d);
                psum += (ad < 1.f) ? 0.5f * d * d : ad - 0.5f;
            }

            // overlap
            float pqn = sqrtf(p[6]*p[6] + p[7]*p[7] + p[8]*p[8] + p[9]*p[9]);
            float tqn = sqrtf(t[6]*t[6] + t[7]*t[7] + t[8]*t[8] + t[9]*t[9]);
            float pri = 1.f / pqn, tri = 1.f / tqn;
            float PR[9], TR[9];
            quat_to_rot(p[6]*pri, p[7]*pri, p[8]*pri, p[9]*pri, PR);
            quat_to_rot(t[6]*tri, t[7]*tri, t[8]*tri, t[9]*tri, TR);

            float ra = 0.f;
            #pragma unroll
            for (int i = 0; i < 9; ++i) ra += PR[i] * TR[i];
            ra = fminf(fmaxf(ra * (1.f/3.f), 0.f), 1.f);

            float ov = ra;
            #pragma unroll
            for (int i = 0; i < 3; ++i) {
                float pe = fabsf(PR[3*i+0]*(p[3]*0.5f) + PR[3*i+1]*(p[4]*0.5f) + PR[3*i+2]*(p[5]*0.5f));
                float te = fabsf(TR[3*i+0]*(t[3]*0.5f) + TR[3*i+1]*(t[4]*0.5f) + TR[3*i+2]*(t[5]*0.5f));
                float cd = fabsf(p[i] - t[i]);
                float ax = fmaxf(fminf(pe, te) * 2.f - cd, 0.f) / (pe + te + EPS_F);
                ov *= ax;
            }
            ov = fminf(fmaxf(ov, 0.f), 1.f);
            osum += ov;
        }

        // drains buf[cur^1] loads (they had the whole compute phase) and
        // fences LDS reads of buf[cur] before it's overwritten next iter.
        __syncthreads();
        if (!more) break;
        c = cn;
        cur ^= 1;
    }

    // ---- reduction: wave shuffle, cross-wave via reused LDS ----
    #pragma unroll
    for (int off = 32; off > 0; off >>= 1) {
        psum += __shfl_down(psum, off);
        osum += __shfl_down(osum, off);
    }
    float* red = reinterpret_cast<float*>(&lds[0][0][0]);  // post-barrier safe
    if (lane == 0) { red[wave] = psum; red[4 + wave] = osum; }
    __syncthreads();
    if (tid == 0) {
        float P = red[0] + red[1] + red[2] + red[3];
        float O = red[4] + red[5] + red[6] + red[7];
        atomicAdd(&acc[0], P);
        atomicAdd(&acc[1], O);
    }
}

__global__ void hybrid_loss_finalize(const float* __restrict__ acc,
                                     float* __restrict__ out) {
    out[0] = acc[0] * (1.f / (10.f * (float)B_ROWS))
           + OVERLAP_WEIGHT * (1.f - acc[1] * (1.f / (float)B_ROWS));
}

extern "C" void kernel_launch(void* const* d_in, const int* in_sizes, int n_in,
                              void* d_out, int out_size, void* d_ws, size_t ws_size,
                              hipStream_t stream) {
    const float4* preds4   = (const float4*)d_in[0];
    const float4* targets4 = (const float4*)d_in[1];
    float* out = (float*)d_out;
    float* acc = (float*)d_ws;

    hipMemsetAsync(acc, 0, 2 * sizeof(float), stream);

    hybrid_loss_main<<<GRID, THREADS, 0, stream>>>(preds4, targets4, acc);
    hybrid_loss_finalize<<<1, 1, 0, stream>>>(acc, out);
}